// Round 10
// baseline (82.774 us; speedup 1.0000x reference)
//
#include <hip/hip_runtime.h>

#define BB 8
#define CC 256
#define HH 96
#define WW 96
#define HWW (HH*WW)
#define NLOC 256        // local prototypes (MFMA path)
#define PPAD 257        // + global prototype
#define THRESH 0.95f
#define NORM_EPS 1e-4f

typedef __attribute__((ext_vector_type(8))) short bf16x8;
typedef __attribute__((ext_vector_type(4))) float f32x4;

// ---- fused kernel 0+1: mask pooling (8 blocks) + feature pooling (2048) ----
__global__ void k01(const float* __restrict__ sup_fts,
                    const float* __restrict__ sup_mask,
                    const float* __restrict__ true_bg,
                    float* __restrict__ protos,
                    float* __restrict__ validf,
                    float* __restrict__ masksum) {
    __shared__ float red[256];
    int blk = blockIdx.x;
    int t = threadIdx.x;
    if (blk < BB * CC) {
        int b = blk >> 8, c = blk & 255;
        int gy = t >> 4, gx = t & 15;
        const float* fb = sup_fts + ((size_t)b * CC + c) * HWW;
        const float* mb = sup_mask + (size_t)b * HWW;
        int base = gy * 6 * WW + gx * 6;
        float fs = 0.f, fm = 0.f;
        for (int r = 0; r < 6; ++r) {
            const float* rowf = fb + base + r * WW;
            const float* rowm = mb + base + r * WW;
#pragma unroll
            for (int h = 0; h < 3; ++h) {
                float2 v  = *(const float2*)(rowf + 2 * h);
                float2 mk = *(const float2*)(rowm + 2 * h);
                fs += v.x + v.y;
                fm = fmaf(v.x, mk.x, fm);
                fm = fmaf(v.y, mk.y, fm);
            }
        }
        protos[((size_t)b * PPAD + t) * CC + c] = fs * (1.f / 36.f);
        red[t] = fm;
        __syncthreads();
        for (int off = 128; off > 0; off >>= 1) {
            if (t < off) red[t] += red[t + off];
            __syncthreads();
        }
        if (t == 0) protos[((size_t)b * PPAD + 256) * CC + c] = red[0];
    } else {
        int b = blk - BB * CC;
        int gy = t >> 4, gx = t & 15;
        const float* mb = sup_mask + (size_t)b * HWW;
        const float* gb = true_bg  + (size_t)b * HWW;
        int base = gy * 6 * WW + gx * 6;
        float ms = 0.f, bs = 0.f;
        for (int r = 0; r < 6; ++r) {
            const float* rowm = mb + base + r * WW;
            const float* rowg = gb + base + r * WW;
#pragma unroll
            for (int h = 0; h < 3; ++h) {
                float2 mk = *(const float2*)(rowm + 2 * h);
                float2 bg2 = *(const float2*)(rowg + 2 * h);
                ms += mk.x + mk.y;
                bs += bg2.x + bg2.y;
            }
        }
        float mmean = ms * (1.f / 36.f);
        float bmean = bs * (1.f / 36.f);
        validf[b * PPAD + t] = (mmean > THRESH && bmean < 0.5f) ? 1.f : 0.f;
        if (t == 0) validf[b * PPAD + 256] = 1.f;
        red[t] = ms;
        __syncthreads();
        for (int off = 128; off > 0; off >>= 1) {
            if (t < off) red[t] += red[t + off];
            __syncthreads();
        }
        if (t == 0) masksum[b] = red[0];
    }
}

// ------- kernel 2: finish gproto + normalize + emit bf16 hi/lo B-image ------
// Bimg layout (ushorts): [B][8 kc][2 hilo][256 p][32 j]
__global__ void k2_norm(float* __restrict__ protos,
                        const float* __restrict__ masksum,
                        unsigned short* __restrict__ Bimg) {
    int bp = blockIdx.x;
    int b = bp / PPAD;
    int p = bp - b * PPAD;
    int t = threadIdx.x;            // channel
    float v = protos[((size_t)b * PPAD + p) * CC + t];
    if (p == 256) v = v / (masksum[b] + 1e-5f);
    __shared__ float red[256];
    red[t] = v * v;
    __syncthreads();
    for (int off = 128; off > 0; off >>= 1) {
        if (t < off) red[t] += red[t + off];
        __syncthreads();
    }
    float norm = sqrtf(red[0]);
    float vn = v / fmaxf(norm, NORM_EPS);
    protos[((size_t)b * PPAD + p) * CC + t] = vn;
    if (p < NLOC) {
        unsigned int u = __float_as_uint(vn);
        unsigned short hi = (unsigned short)(u >> 16);          // truncation
        float lo = vn - __uint_as_float(u & 0xffff0000u);       // exact
        unsigned int ul = __float_as_uint(lo);
        unsigned short lob = (unsigned short)((ul + 0x7fffu + ((ul >> 16) & 1u)) >> 16); // RNE
        int kc = t >> 5, j = t & 31;
        size_t base = ((size_t)(b * 8 + kc) * 2) * 8192;
        Bimg[base + (size_t)p * 32 + j] = hi;                   // hilo=0
        Bimg[base + 8192 + (size_t)p * 32 + j] = lob;           // hilo=1
    }
}

// ---------------- kernel 3: MFMA dists + masked softmax + weighted sum ------
// Round-8 structure (512 thr = 8 waves, 64 px, wave owns 32 protos, q split-
// staged in LDS dbuf via uint4 rows, B streamed L2->regs, lgkm-only LBAR)
// with the TWO remaining poisons removed:
//  (a) __launch_bounds__(512, 2): round 8's (512,4) forced VGPR<=64 and
//      spilled ~2.3MB/dispatch (WRITE_SIZE 2592KB vs 288KB output); spill
//      reloads share the in-order vmcnt -> they drained the q/B prefetch
//      every kc. Cap 256 VGPR: no spill.
//  (b) q prefetch 3 kc deep (r8 was 2): issue-to-use distance ~3 kc-phases
//      (~1800+ cyc) > 900-cyc HBM latency -> SPLITW never stalls on q.
#define LBAR()  do {                                             \
        asm volatile("s_waitcnt lgkmcnt(0)" ::: "memory");       \
        __builtin_amdgcn_sched_barrier(0);                       \
        __builtin_amdgcn_s_barrier();                            \
        __builtin_amdgcn_sched_barrier(0);                       \
    } while (0)

__global__ __launch_bounds__(512, 2)
void k3_mfma(const float* __restrict__ qry,
             const unsigned short* __restrict__ Bimg,
             const float* __restrict__ protos_n,
             const float* __restrict__ validf,
             float* __restrict__ out) {
    // [buf][64 px rows of 72 ushorts: 8 kquads x (4 hi | 4 lo), 8-ushort pad]
    __shared__ alignas(16) unsigned short Qlds[2][4608];   // 18432 B
    __shared__ float nrm_l[8][64], gac_l[8][64];
    __shared__ float S_l[8][64], N_l[8][64];
    __shared__ float rn_s[64], gd_s[64];

    int bid = blockIdx.x;
    int b = bid / 144;
    int tile = bid - b * 144;
    int t = threadIdx.x;              // 0..511
    int lane = t & 63;
    int w = t >> 6;                   // wave 0..7
    int g = lane >> 4;                // k-group
    int n = lane & 15;                // frag 16-lane index
    int px0 = tile * 64;

    int spx = t & 63;                 // staging: pixel owned by this thread
    int kq  = t >> 6;                 // staging: k-quad (4 channels) 0..7

    const float* qb = qry + (size_t)b * CC * HWW + px0 + spx;
    const float* gp = protos_n + ((size_t)b * PPAD + 256) * CC;
    const unsigned short* Bb = Bimg + (size_t)b * 8 * 2 * 8192;

    f32x4 acc[4][2];                  // [px-sub][ct]: 64px x 32 protos
#pragma unroll
    for (int s = 0; s < 4; ++s)
#pragma unroll
        for (int c = 0; c < 2; ++c) acc[s][c] = (f32x4){0.f, 0.f, 0.f, 0.f};

    float nrm = 0.f, gac = 0.f;
    float qs[3][4], gpv[3][4];
    bf16x8 BH[2][2], BL[2][2];        // [buf][ct] proto frags

#define QLOADN(KC, SLOT)                                                      \
    {                                                                         \
        int c0 = (KC) * 32 + kq * 4;                                          \
        _Pragma("unroll")                                                     \
        for (int j = 0; j < 4; ++j) {                                         \
            qs[SLOT][j]  = qb[(size_t)(c0 + j) * HWW];                        \
            gpv[SLOT][j] = gp[c0 + j];                                        \
        }                                                                     \
    }

#define LOADB(KC, BUF)                                                        \
    {                                                                         \
        _Pragma("unroll")                                                     \
        for (int ct = 0; ct < 2; ++ct) {                                      \
            const unsigned short* p0 = Bb + (size_t)(KC) * 16384 +            \
                                       (w * 32 + ct * 16 + n) * 32 + g * 8;   \
            BH[BUF][ct] = *(const bf16x8*)(p0);                               \
            BL[BUF][ct] = *(const bf16x8*)(p0 + 8192);                        \
        }                                                                     \
    }

#define SPLITW(SLOT, BUF)                                                     \
    {                                                                         \
        unsigned int h[4], l[4];                                              \
        _Pragma("unroll")                                                     \
        for (int j = 0; j < 4; ++j) {                                         \
            float qv = qs[SLOT][j];                                           \
            unsigned int u = __float_as_uint(qv);                             \
            h[j] = u >> 16;                                                   \
            float lof = qv - __uint_as_float(u & 0xffff0000u);                \
            unsigned int ul = __float_as_uint(lof);                           \
            l[j] = (ul + 0x7fffu + ((ul >> 16) & 1u)) >> 16;                  \
            nrm = fmaf(qv, qv, nrm);                                          \
            gac = fmaf(qv, gpv[SLOT][j], gac);                                \
        }                                                                     \
        uint4 pk;                                                             \
        pk.x = h[0] | (h[1] << 16); pk.y = h[2] | (h[3] << 16);               \
        pk.z = l[0] | (l[1] << 16); pk.w = l[2] | (l[3] << 16);               \
        *(uint4*)&Qlds[BUF][spx * 72 + kq * 8] = pk;                          \
    }

    // ---- prologue: 3-deep q + 2-deep B prefetch, split kc=0, publish ----
    QLOADN(0, 0);
    QLOADN(1, 1);
    QLOADN(2, 2);
    LOADB(0, 0);
    LOADB(1, 1);
    SPLITW(0, 0);                 // waits q(0) only (everything else younger)
    LBAR();

    // ---- main loop: 1 lgkm-only barrier per kc; prefetch survives it ----
#pragma unroll
    for (int kc = 0; kc < 8; ++kc) {
        if (kc + 3 < 8) QLOADN(kc + 3, (kc + 3) % 3);
#pragma unroll
        for (int sub = 0; sub < 4; ++sub) {
            const unsigned short* rp = &Qlds[kc & 1][(sub * 16 + n) * 72 + g * 16];
            uint4 Aq = *(const uint4*)rp;
            uint4 Bq = *(const uint4*)(rp + 8);
            union { bf16x8 v; unsigned int u[4]; } QH, QL;
            QH.u[0] = Aq.x; QH.u[1] = Aq.y; QH.u[2] = Bq.x; QH.u[3] = Bq.y;
            QL.u[0] = Aq.z; QL.u[1] = Aq.w; QL.u[2] = Bq.z; QL.u[3] = Bq.w;
#pragma unroll
            for (int ct = 0; ct < 2; ++ct) {
                acc[sub][ct] = __builtin_amdgcn_mfma_f32_16x16x32_bf16(QH.v, BH[kc & 1][ct], acc[sub][ct], 0, 0, 0);
                acc[sub][ct] = __builtin_amdgcn_mfma_f32_16x16x32_bf16(QL.v, BH[kc & 1][ct], acc[sub][ct], 0, 0, 0);
                acc[sub][ct] = __builtin_amdgcn_mfma_f32_16x16x32_bf16(QH.v, BL[kc & 1][ct], acc[sub][ct], 0, 0, 0);
            }
        }
        if (kc + 2 < 8) LOADB(kc + 2, kc & 1);   // refill just-consumed B buf
        if (kc + 1 < 8) {
            SPLITW((kc + 1) % 3, (kc + 1) & 1);  // q(kc+1) -> other Q buf
            LBAR();
        }
    }

    // ---- |q|^2 and gproto-dot reduction (8 k-quad partials per px) ----
    nrm_l[kq][spx] = nrm;
    gac_l[kq][spx] = gac;
    __syncthreads();
    if (t < 64) {
        float n2 = 0.f, gs = 0.f;
#pragma unroll
        for (int i = 0; i < 8; ++i) { n2 += nrm_l[i][t]; gs += gac_l[i][t]; }
        float rn = 1.f / fmaxf(sqrtf(n2), NORM_EPS);
        rn_s[t] = rn;
        gd_s[t] = gs * rn;
    }
    __syncthreads();

    // ---- per-wave softmax partials (fixed shift 1.1; 32 protos/wave) ----
    // D-map: proto = 32w + 16ct + n (col), px = 16sub + 4g + r (row).
    float vf0 = validf[b * PPAD + w * 32 + n];
    float vf1 = validf[b * PPAD + w * 32 + 16 + n];
#pragma unroll
    for (int sub = 0; sub < 4; ++sub) {
#pragma unroll
        for (int r = 0; r < 4; ++r) {
            int px = sub * 16 + 4 * g + r;
            float rnv = rn_s[px];
            float d0 = acc[sub][0][r] * rnv;
            float d1 = acc[sub][1][r] * rnv;
            float l0 = (vf0 != 0.f) ? d0 : -1e30f;
            float l1 = (vf1 != 0.f) ? d1 : -1e30f;
            float e0 = __expf(l0 - 1.1f);
            float e1 = __expf(l1 - 1.1f);
            float s = e0 + e1;
            float nn = fmaf(e0, l0, e1 * l1);
#pragma unroll
            for (int m = 1; m < 16; m <<= 1) {
                s  += __shfl_xor(s, m);
                nn += __shfl_xor(nn, m);
            }
            if (n == 0) { S_l[w][px] = s; N_l[w][px] = nn; }
        }
    }
    __syncthreads();

    // ---- final merge: 8 wave-partials + global proto (once), store ----
    if (t < 64) {
        float gdv = gd_s[t];
        float eg = __expf(gdv - 1.1f);
        float S = eg, N = eg * gdv;
#pragma unroll
        for (int i = 0; i < 8; ++i) { S += S_l[i][t]; N += N_l[i][t]; }
        out[(size_t)b * HWW + px0 + t] = N / S;
    }

#undef QLOADN
#undef LOADB
#undef SPLITW
}

extern "C" void kernel_launch(void* const* d_in, const int* in_sizes, int n_in,
                              void* d_out, int out_size, void* d_ws, size_t ws_size,
                              hipStream_t stream) {
    const float* qry = (const float*)d_in[0];
    const float* sup = (const float*)d_in[1];
    const float* msk = (const float*)d_in[2];
    const float* bg  = (const float*)d_in[3];
    float* out = (float*)d_out;

    float* ws = (float*)d_ws;
    float* protos  = ws;                                   // [B][257][256] f32
    float* validf  = protos + (size_t)BB * PPAD * CC;      // [B][257]
    float* masksum = validf + (size_t)BB * PPAD;           // [B]
    unsigned short* Bimg = (unsigned short*)(masksum + BB); // [B][8][2][256][32] ushorts

    hipLaunchKernelGGL(k01, dim3(BB * CC + BB), dim3(256), 0, stream,
                       sup, msk, bg, protos, validf, masksum);
    hipLaunchKernelGGL(k2_norm, dim3(BB * PPAD), dim3(256), 0, stream, protos, masksum, Bimg);
    hipLaunchKernelGGL(k3_mfma, dim3(BB * (HWW / 64)), dim3(512), 0, stream,
                       qry, Bimg, protos, validf, out);
}

// Round 11
// 80.794 us; speedup vs baseline: 1.0245x; 1.0245x over previous
//
#include <hip/hip_runtime.h>

#define BB 8
#define CC 256
#define HH 96
#define WW 96
#define HWW (HH*WW)
#define NLOC 256        // local prototypes (MFMA path)
#define PPAD 257        // + global prototype
#define THRESH 0.95f
#define NORM_EPS 1e-4f

typedef __attribute__((ext_vector_type(8))) _Float16 f16x8;
typedef __attribute__((ext_vector_type(4))) float f32x4;

union H16 { _Float16 f; unsigned short u; };

// ---- fused kernel 0+1: mask pooling (8 blocks) + feature pooling (2048) ----
__global__ void k01(const float* __restrict__ sup_fts,
                    const float* __restrict__ sup_mask,
                    const float* __restrict__ true_bg,
                    float* __restrict__ protos,
                    float* __restrict__ validf,
                    float* __restrict__ masksum) {
    __shared__ float red[256];
    int blk = blockIdx.x;
    int t = threadIdx.x;
    if (blk < BB * CC) {
        int b = blk >> 8, c = blk & 255;
        int gy = t >> 4, gx = t & 15;
        const float* fb = sup_fts + ((size_t)b * CC + c) * HWW;
        const float* mb = sup_mask + (size_t)b * HWW;
        int base = gy * 6 * WW + gx * 6;
        float fs = 0.f, fm = 0.f;
        for (int r = 0; r < 6; ++r) {
            const float* rowf = fb + base + r * WW;
            const float* rowm = mb + base + r * WW;
#pragma unroll
            for (int h = 0; h < 3; ++h) {
                float2 v  = *(const float2*)(rowf + 2 * h);
                float2 mk = *(const float2*)(rowm + 2 * h);
                fs += v.x + v.y;
                fm = fmaf(v.x, mk.x, fm);
                fm = fmaf(v.y, mk.y, fm);
            }
        }
        protos[((size_t)b * PPAD + t) * CC + c] = fs * (1.f / 36.f);
        red[t] = fm;
        __syncthreads();
        for (int off = 128; off > 0; off >>= 1) {
            if (t < off) red[t] += red[t + off];
            __syncthreads();
        }
        if (t == 0) protos[((size_t)b * PPAD + 256) * CC + c] = red[0];
    } else {
        int b = blk - BB * CC;
        int gy = t >> 4, gx = t & 15;
        const float* mb = sup_mask + (size_t)b * HWW;
        const float* gb = true_bg  + (size_t)b * HWW;
        int base = gy * 6 * WW + gx * 6;
        float ms = 0.f, bs = 0.f;
        for (int r = 0; r < 6; ++r) {
            const float* rowm = mb + base + r * WW;
            const float* rowg = gb + base + r * WW;
#pragma unroll
            for (int h = 0; h < 3; ++h) {
                float2 mk = *(const float2*)(rowm + 2 * h);
                float2 bg2 = *(const float2*)(rowg + 2 * h);
                ms += mk.x + mk.y;
                bs += bg2.x + bg2.y;
            }
        }
        float mmean = ms * (1.f / 36.f);
        float bmean = bs * (1.f / 36.f);
        validf[b * PPAD + t] = (mmean > THRESH && bmean < 0.5f) ? 1.f : 0.f;
        if (t == 0) validf[b * PPAD + 256] = 1.f;
        red[t] = ms;
        __syncthreads();
        for (int off = 128; off > 0; off >>= 1) {
            if (t < off) red[t] += red[t + off];
            __syncthreads();
        }
        if (t == 0) masksum[b] = red[0];
    }
}

// ------- kernel 2: finish gproto + normalize + emit SINGLE-fp16 P-image -----
// Pimg layout (fp16 bits): [B][8 kc][256 p][32 j]
__global__ void k2_norm(float* __restrict__ protos,
                        const float* __restrict__ masksum,
                        unsigned short* __restrict__ Pimg) {
    int bp = blockIdx.x;
    int b = bp / PPAD;
    int p = bp - b * PPAD;
    int t = threadIdx.x;            // channel
    float v = protos[((size_t)b * PPAD + p) * CC + t];
    if (p == 256) v = v / (masksum[b] + 1e-5f);
    __shared__ float red[256];
    red[t] = v * v;
    __syncthreads();
    for (int off = 128; off > 0; off >>= 1) {
        if (t < off) red[t] += red[t + off];
        __syncthreads();
    }
    float norm = sqrtf(red[0]);
    float vn = v / fmaxf(norm, NORM_EPS);
    protos[((size_t)b * PPAD + p) * CC + t] = vn;
    if (p < NLOC) {
        H16 h; h.f = (_Float16)vn;            // RNE, err 2^-11 (verified r9)
        int kc = t >> 5, j = t & 31;
        Pimg[(size_t)(b * 8 + kc) * 8192 + p * 32 + j] = h.u;
    }
}

// ---------------- kernel 3: MFMA dists + masked softmax + weighted sum ------
// Block = 512 thr = 8 waves, 64 px; wave w owns protos [32w,32w+32).
// ONE barrier total: stage ALL 256 ch of q (fp16 hi/lo exact split, 64KB LDS,
// XOR-swizzled slot = kquad ^ perm(row)) -> __syncthreads -> barrier-FREE
// marathon: 8 kc x {ds_read Q frags, 2-deep L2 B-stream, 16 f16 MFMAs}.
// Numerics = round-9 (verified absmax 1.22e-4): proto single fp16,
// q = fp16 hi + fp16 lo (exact residual), 2 MFMAs per 16x16x32 tile.
// Loop waits: lgkmcnt (LDS) + vmcnt counting ONLY the B stream.
__global__ __launch_bounds__(512, 2)
void k3_mfma(const float* __restrict__ qry,
             const unsigned short* __restrict__ Pimg,
             const float* __restrict__ protos_n,
             const float* __restrict__ validf,
             float* __restrict__ out) {
    // rows = 64 px, each row 64 kquads x 16B {4ch hi (8B) | 4ch lo (8B)}
    __shared__ alignas(16) unsigned short Qlds[64 * 512];   // 64 KB
    __shared__ float nrm_l[8][64], gac_l[8][64];
    __shared__ float S_l[8][64], N_l[8][64];
    __shared__ float rn_s[64], gd_s[64];

    int bid = blockIdx.x;
    int b = bid / 144;
    int tile = bid - b * 144;
    int t = threadIdx.x;              // 0..511
    int lane = t & 63;
    int w = t >> 6;                   // wave 0..7
    int g = lane >> 4;                // k-group
    int n = lane & 15;                // frag 16-lane index
    int px0 = tile * 64;
    int spx = lane;                   // staging: pixel owned by this thread

    const float* qb = qry + (size_t)b * CC * HWW + px0 + spx;
    const float* gp = protos_n + ((size_t)b * PPAD + 256) * CC;
    const unsigned short* Pb = Pimg + (size_t)b * 8 * 8192;

    // ---- stage q: 32 channels per thread (j=0..7, 4 ch each), exact split --
    float nrm = 0.f, gac = 0.f;
    int permw = ((spx & 15) << 2) | (spx >> 4);      // bijective 6-bit perm
#pragma unroll
    for (int j = 0; j < 8; ++j) {
        int c0 = j * 32 + w * 4;
        float v[4];
#pragma unroll
        for (int i = 0; i < 4; ++i) v[i] = qb[(size_t)(c0 + i) * HWW];
        unsigned int hh[4], ll[4];
#pragma unroll
        for (int i = 0; i < 4; ++i) {
            H16 x; x.f = (_Float16)v[i];             // hi (RNE)
            float lof = v[i] - (float)x.f;           // exact residual
            H16 y; y.f = (_Float16)lof;              // lo
            hh[i] = x.u; ll[i] = y.u;
            nrm = fmaf(v[i], v[i], nrm);
            gac = fmaf(v[i], gp[c0 + i], gac);
        }
        uint4 pk;
        pk.x = hh[0] | (hh[1] << 16); pk.y = hh[2] | (hh[3] << 16);
        pk.z = ll[0] | (ll[1] << 16); pk.w = ll[2] | (ll[3] << 16);
        int kq = j * 8 + w;                          // kquad index 0..63
        int slot = kq ^ permw;                       // conflict-free write
        *(uint4*)&Qlds[spx * 512 + slot * 8] = pk;
    }
    __syncthreads();                 // THE ONLY BLOCK-WIDE BARRIER

    // ---- accumulators + 2-deep B stream (the loop's only VMEM) ----
    f32x4 acc[4][2];
#pragma unroll
    for (int s = 0; s < 4; ++s)
#pragma unroll
        for (int c = 0; c < 2; ++c) acc[s][c] = (f32x4){0.f, 0.f, 0.f, 0.f};
    f16x8 Bf[2][2];

#define LOADB(KC, BUF)                                                        \
    {                                                                         \
        _Pragma("unroll")                                                     \
        for (int ct = 0; ct < 2; ++ct)                                        \
            Bf[BUF][ct] = *(const f16x8*)(Pb + (size_t)(KC) * 8192 +          \
                                          (w * 32 + ct * 16 + n) * 32 + g * 8); \
    }

    LOADB(0, 0);
    LOADB(1, 1);

    // ---- barrier-free MFMA marathon: 8 kc x 4 sub x 2 ct x 2 split ----
#pragma unroll
    for (int kc = 0; kc < 8; ++kc) {
#pragma unroll
        for (int sub = 0; sub < 4; ++sub) {
            int row = sub * 16 + n;
            int permr = ((row & 15) << 2) | (row >> 4);
            int slot0 = (kc * 8 + g * 2) ^ permr;    // kquad even
            const unsigned short* rp = &Qlds[row * 512];
            uint4 Aq = *(const uint4*)&rp[slot0 * 8];
            uint4 Bq = *(const uint4*)&rp[(slot0 ^ 1) * 8];   // kquad+1
            union { f16x8 v; unsigned int u[4]; } QH, QL;
            QH.u[0] = Aq.x; QH.u[1] = Aq.y; QH.u[2] = Bq.x; QH.u[3] = Bq.y;
            QL.u[0] = Aq.z; QL.u[1] = Aq.w; QL.u[2] = Bq.z; QL.u[3] = Bq.w;
#pragma unroll
            for (int ct = 0; ct < 2; ++ct) {
                acc[sub][ct] = __builtin_amdgcn_mfma_f32_16x16x32_f16(QH.v, Bf[kc & 1][ct], acc[sub][ct], 0, 0, 0);
                acc[sub][ct] = __builtin_amdgcn_mfma_f32_16x16x32_f16(QL.v, Bf[kc & 1][ct], acc[sub][ct], 0, 0, 0);
            }
        }
        if (kc + 2 < 8) LOADB(kc + 2, kc & 1);       // refill consumed buf
    }
#undef LOADB

    // ---- |q|^2 and gproto-dot reduction (8 ch-group partials per px) ----
    nrm_l[w][spx] = nrm;
    gac_l[w][spx] = gac;
    __syncthreads();
    if (t < 64) {
        float n2 = 0.f, gs = 0.f;
#pragma unroll
        for (int i = 0; i < 8; ++i) { n2 += nrm_l[i][t]; gs += gac_l[i][t]; }
        float rn = 1.f / fmaxf(sqrtf(n2), NORM_EPS);
        rn_s[t] = rn;
        gd_s[t] = gs * rn;
    }
    __syncthreads();

    // ---- per-wave softmax partials (fixed shift 1.1; 32 protos/wave) ----
    // D-map: proto = 32w + 16ct + n (col), px = 16sub + 4g + r (row).
    float vf0 = validf[b * PPAD + w * 32 + n];
    float vf1 = validf[b * PPAD + w * 32 + 16 + n];
#pragma unroll
    for (int sub = 0; sub < 4; ++sub) {
#pragma unroll
        for (int r = 0; r < 4; ++r) {
            int px = sub * 16 + 4 * g + r;
            float rnv = rn_s[px];
            float d0 = acc[sub][0][r] * rnv;
            float d1 = acc[sub][1][r] * rnv;
            float l0 = (vf0 != 0.f) ? d0 : -1e30f;
            float l1 = (vf1 != 0.f) ? d1 : -1e30f;
            float e0 = __expf(l0 - 1.1f);
            float e1 = __expf(l1 - 1.1f);
            float s = e0 + e1;
            float nn = fmaf(e0, l0, e1 * l1);
#pragma unroll
            for (int m = 1; m < 16; m <<= 1) {
                s  += __shfl_xor(s, m);
                nn += __shfl_xor(nn, m);
            }
            if (n == 0) { S_l[w][px] = s; N_l[w][px] = nn; }
        }
    }
    __syncthreads();

    // ---- final merge: 8 wave-partials + global proto (once), store ----
    if (t < 64) {
        float gdv = gd_s[t];
        float eg = __expf(gdv - 1.1f);
        float S = eg, N = eg * gdv;
#pragma unroll
        for (int i = 0; i < 8; ++i) { S += S_l[i][t]; N += N_l[i][t]; }
        out[(size_t)b * HWW + px0 + t] = N / S;
    }
}

extern "C" void kernel_launch(void* const* d_in, const int* in_sizes, int n_in,
                              void* d_out, int out_size, void* d_ws, size_t ws_size,
                              hipStream_t stream) {
    const float* qry = (const float*)d_in[0];
    const float* sup = (const float*)d_in[1];
    const float* msk = (const float*)d_in[2];
    const float* bg  = (const float*)d_in[3];
    float* out = (float*)d_out;

    float* ws = (float*)d_ws;
    float* protos  = ws;                                   // [B][257][256] f32
    float* validf  = protos + (size_t)BB * PPAD * CC;      // [B][257]
    float* masksum = validf + (size_t)BB * PPAD;           // [B]
    unsigned short* Pimg = (unsigned short*)(masksum + BB); // [B][8][256][32] fp16

    hipLaunchKernelGGL(k01, dim3(BB * CC + BB), dim3(256), 0, stream,
                       sup, msk, bg, protos, validf, masksum);
    hipLaunchKernelGGL(k2_norm, dim3(BB * PPAD), dim3(256), 0, stream, protos, masksum, Pimg);
    hipLaunchKernelGGL(k3_mfma, dim3(BB * (HWW / 64)), dim3(512), 0, stream,
                       qry, Pimg, protos, validf, out);
}

// Round 12
// 68.460 us; speedup vs baseline: 1.2091x; 1.1802x over previous
//
#include <hip/hip_runtime.h>

#define BB 8
#define CC 256
#define HH 96
#define WW 96
#define HWW (HH*WW)
#define NLOC 256        // local prototypes (MFMA path)
#define PPAD 257        // + global prototype
#define THRESH 0.95f
#define NORM_EPS 1e-4f

typedef __attribute__((ext_vector_type(8))) _Float16 f16x8;
typedef __attribute__((ext_vector_type(16))) float f32x16;

union H16 { _Float16 f; unsigned short u; };

// ---- fused kernel 0+1: mask pooling (8 blocks) + feature pooling (2048) ----
__global__ void k01(const float* __restrict__ sup_fts,
                    const float* __restrict__ sup_mask,
                    const float* __restrict__ true_bg,
                    float* __restrict__ protos,
                    float* __restrict__ validf,
                    float* __restrict__ masksum) {
    __shared__ float red[256];
    int blk = blockIdx.x;
    int t = threadIdx.x;
    if (blk < BB * CC) {
        int b = blk >> 8, c = blk & 255;
        int gy = t >> 4, gx = t & 15;
        const float* fb = sup_fts + ((size_t)b * CC + c) * HWW;
        const float* mb = sup_mask + (size_t)b * HWW;
        int base = gy * 6 * WW + gx * 6;
        float fs = 0.f, fm = 0.f;
        for (int r = 0; r < 6; ++r) {
            const float* rowf = fb + base + r * WW;
            const float* rowm = mb + base + r * WW;
#pragma unroll
            for (int h = 0; h < 3; ++h) {
                float2 v  = *(const float2*)(rowf + 2 * h);
                float2 mk = *(const float2*)(rowm + 2 * h);
                fs += v.x + v.y;
                fm = fmaf(v.x, mk.x, fm);
                fm = fmaf(v.y, mk.y, fm);
            }
        }
        protos[((size_t)b * PPAD + t) * CC + c] = fs * (1.f / 36.f);
        red[t] = fm;
        __syncthreads();
        for (int off = 128; off > 0; off >>= 1) {
            if (t < off) red[t] += red[t + off];
            __syncthreads();
        }
        if (t == 0) protos[((size_t)b * PPAD + 256) * CC + c] = red[0];
    } else {
        int b = blk - BB * CC;
        int gy = t >> 4, gx = t & 15;
        const float* mb = sup_mask + (size_t)b * HWW;
        const float* gb = true_bg  + (size_t)b * HWW;
        int base = gy * 6 * WW + gx * 6;
        float ms = 0.f, bs = 0.f;
        for (int r = 0; r < 6; ++r) {
            const float* rowm = mb + base + r * WW;
            const float* rowg = gb + base + r * WW;
#pragma unroll
            for (int h = 0; h < 3; ++h) {
                float2 mk = *(const float2*)(rowm + 2 * h);
                float2 bg2 = *(const float2*)(rowg + 2 * h);
                ms += mk.x + mk.y;
                bs += bg2.x + bg2.y;
            }
        }
        float mmean = ms * (1.f / 36.f);
        float bmean = bs * (1.f / 36.f);
        validf[b * PPAD + t] = (mmean > THRESH && bmean < 0.5f) ? 1.f : 0.f;
        if (t == 0) validf[b * PPAD + 256] = 1.f;
        red[t] = ms;
        __syncthreads();
        for (int off = 128; off > 0; off >>= 1) {
            if (t < off) red[t] += red[t + off];
            __syncthreads();
        }
        if (t == 0) masksum[b] = red[0];
    }
}

// ------- kernel 2: finish gproto + normalize + emit fp16 proto image --------
// Pimg layout (fp16): [B][16 kstep][2 khalf][8 tile][32 col][8 e]
//   element = proto (tile*32+col), channel (kstep*16 + khalf*8 + e)
__global__ void k2_norm(float* __restrict__ protos,
                        const float* __restrict__ masksum,
                        unsigned short* __restrict__ Pimg) {
    int bp = blockIdx.x;
    int b = bp / PPAD;
    int p = bp - b * PPAD;
    int t = threadIdx.x;            // channel
    float v = protos[((size_t)b * PPAD + p) * CC + t];
    if (p == 256) v = v / (masksum[b] + 1e-5f);
    __shared__ float red[256];
    red[t] = v * v;
    __syncthreads();
    for (int off = 128; off > 0; off >>= 1) {
        if (t < off) red[t] += red[t + off];
        __syncthreads();
    }
    float norm = sqrtf(red[0]);
    float vn = v / fmaxf(norm, NORM_EPS);
    protos[((size_t)b * PPAD + p) * CC + t] = vn;
    if (p < NLOC) {
        H16 h; h.f = (_Float16)vn;            // RNE, err 2^-11 (verified r9/r11)
        int kstep = t >> 4, khalf = (t >> 3) & 1, e = t & 7;
        int tile = p >> 5, col = p & 31;
        size_t idx = ((((size_t)b * 16 + kstep) * 2 + khalf) * 8 + tile) * 256
                     + col * 8 + e;
        Pimg[idx] = h.u;
    }
}

// ---------------- kernel 3: MFMA dists + masked softmax + weighted sum ------
// Block = 256 thr = 4 waves, 32 px; wave w owns protos [64w, 64w+64) as TWO
// 32x32 tiles. v_mfma_f32_32x32x16_f16: one 2KB A-read (q hi+lo from LDS)
// feeds 4 MFMAs = 64 FLOP per LDS byte (4x round-11's 16x16 economy).
// Q LDS layout [kq][px][4 f16] planes: b64 writes/reads are px*8B -> 2-way
// bank aliasing max (free). Protos stream from L2 (1MB total, loop's ONLY
// VMEM, 2-step lookahead). ONE barrier before the loop, none inside.
// Numerics: proto single fp16, q = fp16 hi + exact fp16 lo residual.
__global__ __launch_bounds__(256, 4)
void k3_mfma(const float* __restrict__ qry,
             const unsigned short* __restrict__ Pimg,
             const float* __restrict__ protos_n,
             const float* __restrict__ validf,
             float* __restrict__ out) {
    __shared__ alignas(16) unsigned short Qhi[64 * 128];   // [kq][px][4] = 16 KB
    __shared__ alignas(16) unsigned short Qlo[64 * 128];   // 16 KB
    __shared__ float red_n[8][32], red_g[8][32];
    __shared__ float rn_s[32], gd_s[32];
    __shared__ float S_l[4][32], N_l[4][32];

    int blk = blockIdx.x;
    int b = blk & 7;                  // batch <-> XCD affinity
    int tpx = blk >> 3;               // 0..287
    int px0 = tpx * 32;
    int t = threadIdx.x;              // 0..255
    int l = t & 63;
    int w = t >> 6;                   // wave 0..3
    int col = l & 31;                 // proto-col within tile / px for staging
    int h = l >> 5;                   // k-half lane bit

    int spx = t & 31;                 // staging: pixel
    int cg  = t >> 5;                 // staging: channel group (32 ch each)

    const float* qb = qry + (size_t)b * CC * HWW + px0 + spx;
    const float* gp = protos_n + ((size_t)b * PPAD + 256) * CC;
    const unsigned short* Pb = Pimg + (size_t)b * 65536;

    // ---- stage q (32 ch/thread, 8 kquads): exact fp16 hi/lo split ----
    float nrm = 0.f, gac = 0.f;
#pragma unroll
    for (int j = 0; j < 8; ++j) {
        int c0 = cg * 32 + j * 4;
        float v[4], gpv[4];
#pragma unroll
        for (int i = 0; i < 4; ++i) { v[i] = qb[(size_t)(c0 + i) * HWW]; gpv[i] = gp[c0 + i]; }
        unsigned int hh[4], ll[4];
#pragma unroll
        for (int i = 0; i < 4; ++i) {
            H16 x; x.f = (_Float16)v[i];             // hi (RNE)
            float lof = v[i] - (float)x.f;           // exact residual
            H16 y; y.f = (_Float16)lof;              // lo
            hh[i] = x.u; ll[i] = y.u;
            nrm = fmaf(v[i], v[i], nrm);
            gac = fmaf(v[i], gpv[i], gac);
        }
        int kq = cg * 8 + j;
        uint2 Hp, Lp;
        Hp.x = hh[0] | (hh[1] << 16); Hp.y = hh[2] | (hh[3] << 16);
        Lp.x = ll[0] | (ll[1] << 16); Lp.y = ll[2] | (ll[3] << 16);
        *(uint2*)&Qhi[kq * 128 + spx * 4] = Hp;      // px*8B -> 2-way max (free)
        *(uint2*)&Qlo[kq * 128 + spx * 4] = Lp;
    }
    red_n[cg][spx] = nrm;
    red_g[cg][spx] = gac;
    __syncthreads();                  // the ONLY pre-loop barrier
    if (t < 32) {
        float n2 = 0.f, gs = 0.f;
#pragma unroll
        for (int i = 0; i < 8; ++i) { n2 += red_n[i][t]; gs += red_g[i][t]; }
        float rn = 1.f / fmaxf(sqrtf(n2), NORM_EPS);
        rn_s[t] = rn;
        gd_s[t] = gs * rn;
    }

    // ---- accumulators + B stream (loop's only VMEM; L2-resident 128KB/b) --
    f32x16 acc[2];
#pragma unroll
    for (int i = 0; i < 16; ++i) { acc[0][i] = 0.f; acc[1][i] = 0.f; }
    f16x8 Bf[2][2];                   // [buf][tile]

#define LOADB(KS, BUF)                                                        \
    {                                                                         \
        _Pragma("unroll")                                                     \
        for (int ti = 0; ti < 2; ++ti)                                        \
            Bf[BUF][ti] = *(const f16x8*)(Pb +                                \
                ((((size_t)(KS) * 2 + h) * 8 + (w * 2 + ti)) * 32 + col) * 8);\
    }

    LOADB(0, 0);
    LOADB(1, 1);

    // ---- barrier-free marathon: 16 K-steps x {1 A-read, 4 MFMA} ----
#pragma unroll
    for (int ks = 0; ks < 16; ++ks) {
        int kq0 = ks * 4 + h * 2;
        uint2 h0 = *(const uint2*)&Qhi[kq0 * 128 + col * 4];
        uint2 h1 = *(const uint2*)&Qhi[(kq0 + 1) * 128 + col * 4];
        uint2 l0 = *(const uint2*)&Qlo[kq0 * 128 + col * 4];
        uint2 l1 = *(const uint2*)&Qlo[(kq0 + 1) * 128 + col * 4];
        union { f16x8 v; unsigned int u[4]; } QH, QL;
        QH.u[0] = h0.x; QH.u[1] = h0.y; QH.u[2] = h1.x; QH.u[3] = h1.y;
        QL.u[0] = l0.x; QL.u[1] = l0.y; QL.u[2] = l1.x; QL.u[3] = l1.y;
#pragma unroll
        for (int ti = 0; ti < 2; ++ti) {
            acc[ti] = __builtin_amdgcn_mfma_f32_32x32x16_f16(QH.v, Bf[ks & 1][ti], acc[ti], 0, 0, 0);
            acc[ti] = __builtin_amdgcn_mfma_f32_32x32x16_f16(QL.v, Bf[ks & 1][ti], acc[ti], 0, 0, 0);
        }
        if (ks + 2 < 16) LOADB(ks + 2, ks & 1);
    }
#undef LOADB

    __syncthreads();                  // rn_s/gd_s visible; loop VMEM drained

    // ---- softmax epilogue ----
    // D-map (verified m74/m101): col = lane&31 -> proto = w*64 + ti*32 + col;
    // row(px) = (r&3) + 8*(r>>2) + 4*h.
    float vf0 = validf[b * PPAD + w * 64 + col];
    float vf1 = validf[b * PPAD + w * 64 + 32 + col];
#pragma unroll
    for (int r = 0; r < 16; ++r) {
        int row = (r & 3) + 8 * (r >> 2) + 4 * h;
        float rnv = rn_s[row];
        float d0 = acc[0][r] * rnv;
        float d1 = acc[1][r] * rnv;
        float l0 = (vf0 != 0.f) ? d0 : -1e30f;
        float l1 = (vf1 != 0.f) ? d1 : -1e30f;
        float e0 = __expf(l0 - 1.1f);             // masked -> exactly 0
        float e1 = __expf(l1 - 1.1f);
        float s = e0 + e1;
        float nn = fmaf(e0, l0, e1 * l1);
#pragma unroll
        for (int m = 1; m < 32; m <<= 1) {        // reduce over 32 proto-cols
            s  += __shfl_xor(s, m);
            nn += __shfl_xor(nn, m);
        }
        if (col == 0) { S_l[w][row] = s; N_l[w][row] = nn; }
    }
    __syncthreads();

    // ---- final merge: 4 wave-partials + global proto (once), store ----
    if (t < 32) {
        float gdv = gd_s[t];
        float eg = __expf(gdv - 1.1f);
        float S = eg, N = eg * gdv;
#pragma unroll
        for (int i = 0; i < 4; ++i) { S += S_l[i][t]; N += N_l[i][t]; }
        out[(size_t)b * HWW + px0 + t] = N / S;
    }
}

extern "C" void kernel_launch(void* const* d_in, const int* in_sizes, int n_in,
                              void* d_out, int out_size, void* d_ws, size_t ws_size,
                              hipStream_t stream) {
    const float* qry = (const float*)d_in[0];
    const float* sup = (const float*)d_in[1];
    const float* msk = (const float*)d_in[2];
    const float* bg  = (const float*)d_in[3];
    float* out = (float*)d_out;

    float* ws = (float*)d_ws;
    float* protos  = ws;                                   // [B][257][256] f32
    float* validf  = protos + (size_t)BB * PPAD * CC;      // [B][257]
    float* masksum = validf + (size_t)BB * PPAD;           // [B]
    unsigned short* Pimg = (unsigned short*)(masksum + BB); // [B][16][2][8][32][8] fp16

    hipLaunchKernelGGL(k01, dim3(BB * CC + BB), dim3(256), 0, stream,
                       sup, msk, bg, protos, validf, masksum);
    hipLaunchKernelGGL(k2_norm, dim3(BB * PPAD), dim3(256), 0, stream, protos, masksum, Pimg);
    hipLaunchKernelGGL(k3_mfma, dim3(BB * (HWW / 32)), dim3(256), 0, stream,
                       qry, Pimg, protos, validf, out);
}

// Round 13
// 58.219 us; speedup vs baseline: 1.4218x; 1.1759x over previous
//
#include <hip/hip_runtime.h>

#define BB 8
#define CC 256
#define HH 96
#define WW 96
#define HWW (HH*WW)
#define NLOC 256        // local prototypes (MFMA path)
#define PPAD 257        // + global prototype
#define THRESH 0.95f
#define NORM_EPS 1e-4f

typedef __attribute__((ext_vector_type(8))) _Float16 f16x8;
typedef __attribute__((ext_vector_type(16))) float f32x16;

union H16 { _Float16 f; unsigned short u; };

// ---- fused kernel 0+1: mask pooling (8 blocks) + feature pooling (2048) ----
__global__ void k01(const float* __restrict__ sup_fts,
                    const float* __restrict__ sup_mask,
                    const float* __restrict__ true_bg,
                    float* __restrict__ protos,
                    float* __restrict__ validf,
                    float* __restrict__ masksum) {
    __shared__ float red[256];
    int blk = blockIdx.x;
    int t = threadIdx.x;
    if (blk < BB * CC) {
        int b = blk >> 8, c = blk & 255;
        int gy = t >> 4, gx = t & 15;
        const float* fb = sup_fts + ((size_t)b * CC + c) * HWW;
        const float* mb = sup_mask + (size_t)b * HWW;
        int base = gy * 6 * WW + gx * 6;
        float fs = 0.f, fm = 0.f;
        for (int r = 0; r < 6; ++r) {
            const float* rowf = fb + base + r * WW;
            const float* rowm = mb + base + r * WW;
#pragma unroll
            for (int h = 0; h < 3; ++h) {
                float2 v  = *(const float2*)(rowf + 2 * h);
                float2 mk = *(const float2*)(rowm + 2 * h);
                fs += v.x + v.y;
                fm = fmaf(v.x, mk.x, fm);
                fm = fmaf(v.y, mk.y, fm);
            }
        }
        protos[((size_t)b * PPAD + t) * CC + c] = fs * (1.f / 36.f);
        red[t] = fm;
        __syncthreads();
        for (int off = 128; off > 0; off >>= 1) {
            if (t < off) red[t] += red[t + off];
            __syncthreads();
        }
        if (t == 0) protos[((size_t)b * PPAD + 256) * CC + c] = red[0];
    } else {
        int b = blk - BB * CC;
        int gy = t >> 4, gx = t & 15;
        const float* mb = sup_mask + (size_t)b * HWW;
        const float* gb = true_bg  + (size_t)b * HWW;
        int base = gy * 6 * WW + gx * 6;
        float ms = 0.f, bs = 0.f;
        for (int r = 0; r < 6; ++r) {
            const float* rowm = mb + base + r * WW;
            const float* rowg = gb + base + r * WW;
#pragma unroll
            for (int h = 0; h < 3; ++h) {
                float2 mk = *(const float2*)(rowm + 2 * h);
                float2 bg2 = *(const float2*)(rowg + 2 * h);
                ms += mk.x + mk.y;
                bs += bg2.x + bg2.y;
            }
        }
        float mmean = ms * (1.f / 36.f);
        float bmean = bs * (1.f / 36.f);
        validf[b * PPAD + t] = (mmean > THRESH && bmean < 0.5f) ? 1.f : 0.f;
        if (t == 0) validf[b * PPAD + 256] = 1.f;
        red[t] = ms;
        __syncthreads();
        for (int off = 128; off > 0; off >>= 1) {
            if (t < off) red[t] += red[t + off];
            __syncthreads();
        }
        if (t == 0) masksum[b] = red[0];
    }
}

// ------- kernel 2: finish gproto + normalize + emit fp16 proto image --------
// Pimg layout (fp16): [B][16 kstep][2 khalf][8 tile][32 col][8 e]
__global__ void k2_norm(float* __restrict__ protos,
                        const float* __restrict__ masksum,
                        unsigned short* __restrict__ Pimg) {
    int bp = blockIdx.x;
    int b = bp / PPAD;
    int p = bp - b * PPAD;
    int t = threadIdx.x;            // channel
    float v = protos[((size_t)b * PPAD + p) * CC + t];
    if (p == 256) v = v / (masksum[b] + 1e-5f);
    __shared__ float red[256];
    red[t] = v * v;
    __syncthreads();
    for (int off = 128; off > 0; off >>= 1) {
        if (t < off) red[t] += red[t + off];
        __syncthreads();
    }
    float norm = sqrtf(red[0]);
    float vn = v / fmaxf(norm, NORM_EPS);
    protos[((size_t)b * PPAD + p) * CC + t] = vn;
    if (p < NLOC) {
        H16 h; h.f = (_Float16)vn;            // RNE, err 2^-11
        int kstep = t >> 4, khalf = (t >> 3) & 1, e = t & 7;
        int tile = p >> 5, col = p & 31;
        size_t idx = ((((size_t)b * 16 + kstep) * 2 + khalf) * 8 + tile) * 256
                     + col * 8 + e;
        Pimg[idx] = h.u;
    }
}

// ---------------- kernel 3: MFMA dists + masked softmax + weighted sum ------
// Round-12 structure with the q lo-plane DROPPED (single fp16 q, RNE):
//  - numerics: dcos <= 2^-11 worst-case; expected absmax 2.5-3.7e-4 < 4.88e-4
//  - staging conversion VALU halved, LDS 36 -> ~20 KB, MFMA count halved
//  - __launch_bounds__(256, 6): 6 blocks/CU -> 75% occupancy cap (was 50%)
// Everything else identical to r12 (verified D-map, masks, merge).
__global__ __launch_bounds__(256, 6)
void k3_mfma(const float* __restrict__ qry,
             const unsigned short* __restrict__ Pimg,
             const float* __restrict__ protos_n,
             const float* __restrict__ validf,
             float* __restrict__ out) {
    __shared__ alignas(16) unsigned short Qf[64 * 128];    // [kq][px][4 f16] = 16 KB
    __shared__ float red_n[8][32], red_g[8][32];
    __shared__ float rn_s[32], gd_s[32];
    __shared__ float S_l[4][32], N_l[4][32];

    int blk = blockIdx.x;
    int b = blk & 7;                  // batch <-> XCD affinity
    int tpx = blk >> 3;               // 0..287
    int px0 = tpx * 32;
    int t = threadIdx.x;              // 0..255
    int l = t & 63;
    int w = t >> 6;                   // wave 0..3
    int col = l & 31;                 // proto-col within tile / px for staging
    int h = l >> 5;                   // k-half lane bit

    int spx = t & 31;                 // staging: pixel
    int cg  = t >> 5;                 // staging: channel group (32 ch each)

    const float* qb = qry + (size_t)b * CC * HWW + px0 + spx;
    const float* gp = protos_n + ((size_t)b * PPAD + 256) * CC;
    const unsigned short* Pb = Pimg + (size_t)b * 65536;

    // ---- stage q (32 ch/thread, 8 kquads): single fp16 (RNE) ----
    float nrm = 0.f, gac = 0.f;
#pragma unroll
    for (int j = 0; j < 8; ++j) {
        int c0 = cg * 32 + j * 4;
        float v[4], gpv[4];
#pragma unroll
        for (int i = 0; i < 4; ++i) { v[i] = qb[(size_t)(c0 + i) * HWW]; gpv[i] = gp[c0 + i]; }
        unsigned int hh[4];
#pragma unroll
        for (int i = 0; i < 4; ++i) {
            H16 x; x.f = (_Float16)v[i];             // RNE
            hh[i] = x.u;
            nrm = fmaf(v[i], v[i], nrm);
            gac = fmaf(v[i], gpv[i], gac);
        }
        int kq = cg * 8 + j;
        uint2 pk;
        pk.x = hh[0] | (hh[1] << 16); pk.y = hh[2] | (hh[3] << 16);
        *(uint2*)&Qf[kq * 128 + spx * 4] = pk;       // px*8B -> 2-way max (free)
    }
    red_n[cg][spx] = nrm;
    red_g[cg][spx] = gac;
    __syncthreads();                  // the ONLY pre-loop barrier
    if (t < 32) {
        float n2 = 0.f, gs = 0.f;
#pragma unroll
        for (int i = 0; i < 8; ++i) { n2 += red_n[i][t]; gs += red_g[i][t]; }
        float rn = 1.f / fmaxf(sqrtf(n2), NORM_EPS);
        rn_s[t] = rn;
        gd_s[t] = gs * rn;
    }

    // ---- accumulators + B stream (loop's only VMEM; L2-resident 128KB/b) --
    f32x16 acc[2];
#pragma unroll
    for (int i = 0; i < 16; ++i) { acc[0][i] = 0.f; acc[1][i] = 0.f; }
    f16x8 Bf[2][2];                   // [buf][tile]

#define LOADB(KS, BUF)                                                        \
    {                                                                         \
        _Pragma("unroll")                                                     \
        for (int ti = 0; ti < 2; ++ti)                                        \
            Bf[BUF][ti] = *(const f16x8*)(Pb +                                \
                ((((size_t)(KS) * 2 + h) * 8 + (w * 2 + ti)) * 32 + col) * 8);\
    }

    LOADB(0, 0);
    LOADB(1, 1);

    // ---- barrier-free marathon: 16 K-steps x {1 A-read, 2 MFMA} ----
#pragma unroll
    for (int ks = 0; ks < 16; ++ks) {
        int kq0 = ks * 4 + h * 2;
        uint2 a0 = *(const uint2*)&Qf[kq0 * 128 + col * 4];
        uint2 a1 = *(const uint2*)&Qf[(kq0 + 1) * 128 + col * 4];
        union { f16x8 v; unsigned int u[4]; } QA;
        QA.u[0] = a0.x; QA.u[1] = a0.y; QA.u[2] = a1.x; QA.u[3] = a1.y;
#pragma unroll
        for (int ti = 0; ti < 2; ++ti)
            acc[ti] = __builtin_amdgcn_mfma_f32_32x32x16_f16(QA.v, Bf[ks & 1][ti], acc[ti], 0, 0, 0);
        if (ks + 2 < 16) LOADB(ks + 2, ks & 1);
    }
#undef LOADB

    __syncthreads();                  // rn_s/gd_s visible

    // ---- softmax epilogue ----
    // D-map (verified m74/m101): proto = w*64 + ti*32 + col (col = lane&31);
    // row(px) = (r&3) + 8*(r>>2) + 4*h.
    float vf0 = validf[b * PPAD + w * 64 + col];
    float vf1 = validf[b * PPAD + w * 64 + 32 + col];
#pragma unroll
    for (int r = 0; r < 16; ++r) {
        int row = (r & 3) + 8 * (r >> 2) + 4 * h;
        float rnv = rn_s[row];
        float d0 = acc[0][r] * rnv;
        float d1 = acc[1][r] * rnv;
        float l0 = (vf0 != 0.f) ? d0 : -1e30f;
        float l1 = (vf1 != 0.f) ? d1 : -1e30f;
        float e0 = __expf(l0 - 1.1f);             // masked -> exactly 0
        float e1 = __expf(l1 - 1.1f);
        float s = e0 + e1;
        float nn = fmaf(e0, l0, e1 * l1);
#pragma unroll
        for (int m = 1; m < 32; m <<= 1) {        // reduce over 32 proto-cols
            s  += __shfl_xor(s, m);
            nn += __shfl_xor(nn, m);
        }
        if (col == 0) { S_l[w][row] = s; N_l[w][row] = nn; }
    }
    __syncthreads();

    // ---- final merge: 4 wave-partials + global proto (once), store ----
    if (t < 32) {
        float gdv = gd_s[t];
        float eg = __expf(gdv - 1.1f);
        float S = eg, N = eg * gdv;
#pragma unroll
        for (int i = 0; i < 4; ++i) { S += S_l[i][t]; N += N_l[i][t]; }
        out[(size_t)b * HWW + px0 + t] = N / S;
    }
}

extern "C" void kernel_launch(void* const* d_in, const int* in_sizes, int n_in,
                              void* d_out, int out_size, void* d_ws, size_t ws_size,
                              hipStream_t stream) {
    const float* qry = (const float*)d_in[0];
    const float* sup = (const float*)d_in[1];
    const float* msk = (const float*)d_in[2];
    const float* bg  = (const float*)d_in[3];
    float* out = (float*)d_out;

    float* ws = (float*)d_ws;
    float* protos  = ws;                                   // [B][257][256] f32
    float* validf  = protos + (size_t)BB * PPAD * CC;      // [B][257]
    float* masksum = validf + (size_t)BB * PPAD;           // [B]
    unsigned short* Pimg = (unsigned short*)(masksum + BB); // [B][16][2][8][32][8] fp16

    hipLaunchKernelGGL(k01, dim3(BB * CC + BB), dim3(256), 0, stream,
                       sup, msk, bg, protos, validf, masksum);
    hipLaunchKernelGGL(k2_norm, dim3(BB * PPAD), dim3(256), 0, stream, protos, masksum, Pimg);
    hipLaunchKernelGGL(k3_mfma, dim3(BB * (HWW / 32)), dim3(256), 0, stream,
                       qry, Pimg, protos, validf, out);
}